// Round 4
// baseline (944.621 us; speedup 1.0000x reference)
//
#include <hip/hip_runtime.h>
#include <math.h>

#define B 32
#define N1 16384
#define NP1 128
#define NS1 32
#define NP2 32
#define NS2 32

// workspace offsets (in floats)
#define OFF_L1X   0
#define OFF_G1    12288
#define OFF_L1F   405504
#define OFF_L2X   929792
#define OFF_NIDX2 932864
#define OFF_L2F   965632
#define OFF_L3F   1227776

// ---------------------------------------------------------------- FPS (SA1)
// One barrier per round. Per-wave winners go to 16 distinct double-buffered
// LDS slots (plain ds_write_b64 — no same-address atomic serialization);
// every thread scans the 16 slots of the previous round via broadcast reads.
// Point cloud pinned in registers via volatile one-time loads (the compiler
// otherwise rematerializes the global loads inside the 128-round loop:
// R2 showed VGPR_Count=48 < the 64 floats of resident data).
__global__ __launch_bounds__(1024) void k_fps1(const float* __restrict__ xyz,
                                               float* __restrict__ l1x) {
  const int b = blockIdx.x, t = threadIdx.x;
  const float* xb = xyz + (size_t)b * N1 * 3;
  float px[16], py[16], pz[16], dd[16];
  {
    const volatile float* xv = xb;   // volatile: loads can't be re-issued later
#pragma unroll
    for (int j = 0; j < 16; ++j) {
      int idx = t + (j << 10);
      px[j] = xv[idx * 3 + 0]; py[j] = xv[idx * 3 + 1]; pz[j] = xv[idx * 3 + 2];
      dd[j] = 1e10f;
    }
  }
  __shared__ unsigned long long slots[2][16];
  if (t < 16) slots[0][t] = (t == 0) ? 0xFFFFFFFFull : 0ull;  // round-0 winner: idx 0
  __syncthreads();
  for (int it = 0; it < NP1; ++it) {
    // winner of previous round = max over 16 slots (broadcast LDS reads)
    unsigned long long key = slots[it & 1][0];
#pragma unroll
    for (int w = 1; w < 16; ++w) {
      unsigned long long k2 = slots[it & 1][w];
      if (k2 > key) key = k2;
    }
    const int widx = (int)(0xFFFFFFFFu - (unsigned)(key & 0xFFFFFFFFull));
    const float cx = xb[widx * 3 + 0];   // wave-uniform broadcast load (L2-hot)
    const float cy = xb[widx * 3 + 1];
    const float cz = xb[widx * 3 + 2];
    if (t == 0) {
      float* o = l1x + ((size_t)b * NP1 + it) * 3;
      o[0] = cx; o[1] = cy; o[2] = cz;
    }
    // update running min-dist, thread-local argmax (j ascending => lowest idx)
    float bd = -1.f; int bj = 0;
#pragma unroll
    for (int j = 0; j < 16; ++j) {
      float dx = px[j] - cx, dy = py[j] - cy, dz = pz[j] - cz;
      float d = dx * dx + dy * dy + dz * dz;
      float nd = fminf(dd[j], d);
      dd[j] = nd;
      if (nd > bd) { bd = nd; bj = j; }
    }
    unsigned long long mykey =
        ((unsigned long long)__float_as_uint(bd) << 32) |
        (unsigned long long)(0xFFFFFFFFu - (unsigned)(t + (bj << 10)));
#pragma unroll
    for (int off = 32; off > 0; off >>= 1) {
      unsigned long long ok = __shfl_down(mykey, off);
      if (ok > mykey) mykey = ok;
    }
    if ((t & 63) == 0) slots[(it + 1) & 1][t >> 6] = mykey;
    __syncthreads();   // publishes slots for round it+1; done with slots[it&1]
  }
}

// ---------------------------------------------------------------- kNN (SA1)
// Histogram-select on float-bit bins + parallel exact ranking. ~6 barriers
// total (vs ~130 serial extract-min barriers in the round-0 version).
__device__ __forceinline__ float dist3(const float* __restrict__ xb, int idx,
                                       float cx, float cy, float cz,
                                       float& x, float& y, float& z) {
  x = xb[idx * 3 + 0]; y = xb[idx * 3 + 1]; z = xb[idx * 3 + 2];
  float dx = x - cx, dy = y - cy, dz = z - cz;
  return dx * dx + dy * dy + dz * dz;
}

#define KNN_CAP 512
#define NBIN 2048

__global__ __launch_bounds__(256) void k_knn1(const float* __restrict__ xyz,
                                              const float* __restrict__ l1x,
                                              float* __restrict__ g1) {
  const int t = threadIdx.x;
  const int b = blockIdx.x & 31;       // keeps same-batch blocks on one XCD
  const int m = blockIdx.x >> 5;
  const float* xb = xyz + (size_t)b * N1 * 3;
  const float* cp = l1x + ((size_t)b * NP1 + m) * 3;
  const float cx = cp[0], cy = cp[1], cz = cp[2];

  __shared__ int hist[NBIN];
  __shared__ float cd[KNN_CAP]; __shared__ int ci[KNN_CAP];
  __shared__ float cpx[KNN_CAP], cpy[KNN_CAP], cpz[KNN_CAP];
  __shared__ int s_cnt, s_cut;
  __shared__ int wsum[4];

  for (int i = t; i < NBIN; i += 256) hist[i] = 0;
  if (t == 0) { s_cnt = 0; s_cut = NBIN - 1; }
  __syncthreads();

  // pass 1: histogram of monotone float-bit bins (d >= 0 so bits are monotone)
  for (int j = 0; j < 64; ++j) {
    float x, y, z;
    float d = dist3(xb, t + (j << 8), cx, cy, cz, x, y, z);
    atomicAdd(&hist[__float_as_uint(d) >> 20], 1);
  }
  __syncthreads();

  // find cutoff bin: smallest bin with cumulative count >= 32
  {
    int loc = 0;
#pragma unroll
    for (int j = 0; j < 8; ++j) loc += hist[t * 8 + j];
    int v = loc;
#pragma unroll
    for (int off = 1; off < 64; off <<= 1) {
      int u = __shfl_up(v, off);
      if ((t & 63) >= off) v += u;
    }
    if ((t & 63) == 63) wsum[t >> 6] = v;
    __syncthreads();
    int woff = 0;
    for (int w = 0; w < (t >> 6); ++w) woff += wsum[w];
    int incl = v + woff, excl = incl - loc;
    if (excl < NS1 && incl >= NS1) {  // exactly one thread
      int c = excl;
#pragma unroll
      for (int j = 0; j < 8; ++j) {
        c += hist[t * 8 + j];
        if (c >= NS1) { s_cut = t * 8 + j; break; }
      }
    }
  }
  __syncthreads();
  const unsigned cut = (unsigned)s_cut + 1u;  // +1 bin slack vs recompute drift

  // pass 2: collect candidates (cumulative count through cutoff >= 32)
  for (int j = 0; j < 64; ++j) {
    float x, y, z;
    float d = dist3(xb, t + (j << 8), cx, cy, cz, x, y, z);
    if ((__float_as_uint(d) >> 20) <= cut) {
      int p = atomicAdd(&s_cnt, 1);
      if (p < KNN_CAP) { cd[p] = d; ci[p] = t + (j << 8); cpx[p] = x; cpy[p] = y; cpz[p] = z; }
    }
  }
  __syncthreads();
  const int cnt = (s_cnt < KNN_CAP) ? s_cnt : KNN_CAP;

  // exact lexicographic (d, idx) ranking — fully parallel, no serial rounds
  float* gout = g1 + ((size_t)(b * NP1 + m)) * NS1 * 3;
  for (int p = t; p < cnt; p += 256) {
    const float dp = cd[p]; const int ip = ci[p];
    int rank = 0;
    for (int q = 0; q < cnt; ++q) {
      float dq = cd[q];
      rank += (dq < dp || (dq == dp && ci[q] < ip)) ? 1 : 0;
    }
    if (rank < NS1) {
      gout[rank * 3 + 0] = cpx[p] - cx;
      gout[rank * 3 + 1] = cpy[p] - cy;
      gout[rank * 3 + 2] = cpz[p] - cz;
    }
  }
}

// ------------------------------------------------- generic SA-MLP layer (S=32)
// 4s x 4c register tiles, weights LDS-staged in 16-row chunks.
template <int K, int C, int TPT>
__device__ __forceinline__ void sa_layer(const float* __restrict__ W,
                                         const float* __restrict__ bias,
                                         const float* __restrict__ hin, int instride,
                                         float* __restrict__ hout,
                                         unsigned* __restrict__ om,
                                         float* __restrict__ wst, int t) {
  constexpr int CT = C / 4;
  constexpr int NT = 8 * CT;  // (32/4) s-tiles * c-tiles
  float acc[TPT][4][4];
  int s4[TPT], c4[TPT]; bool on[TPT];
#pragma unroll
  for (int p = 0; p < TPT; ++p) {
    int tile = t + p * 256;
    on[p] = tile < NT;
    int tl = on[p] ? tile : 0;
    s4[p] = (tl / CT) * 4; c4[p] = (tl % CT) * 4;
    float4 bb = *(const float4*)(bias + c4[p]);
#pragma unroll
    for (int i = 0; i < 4; ++i) {
      acc[p][i][0] = bb.x; acc[p][i][1] = bb.y; acc[p][i][2] = bb.z; acc[p][i][3] = bb.w;
    }
  }
  for (int k0 = 0; k0 < K; k0 += 16) {
    const int kc = (K - k0 < 16) ? (K - k0) : 16;
    __syncthreads();
    for (int i = t; i < kc * C; i += 256) wst[i] = W[k0 * C + i];
    __syncthreads();
    if (kc == 16) {
#pragma unroll
      for (int kk = 0; kk < 16; ++kk) {
#pragma unroll
        for (int p = 0; p < TPT; ++p) {
          float4 w = *(const float4*)(wst + kk * C + c4[p]);
#pragma unroll
          for (int i = 0; i < 4; ++i) {
            float a = hin[(s4[p] + i) * instride + (k0 + kk)];
            acc[p][i][0] += a * w.x; acc[p][i][1] += a * w.y;
            acc[p][i][2] += a * w.z; acc[p][i][3] += a * w.w;
          }
        }
      }
    } else {
      for (int kk = 0; kk < kc; ++kk) {
#pragma unroll
        for (int p = 0; p < TPT; ++p) {
          float4 w = *(const float4*)(wst + kk * C + c4[p]);
#pragma unroll
          for (int i = 0; i < 4; ++i) {
            float a = hin[(s4[p] + i) * instride + (k0 + kk)];
            acc[p][i][0] += a * w.x; acc[p][i][1] += a * w.y;
            acc[p][i][2] += a * w.z; acc[p][i][3] += a * w.w;
          }
        }
      }
    }
  }
#pragma unroll
  for (int p = 0; p < TPT; ++p) {
    if (!on[p]) continue;
    if (om) {
#pragma unroll
      for (int j = 0; j < 4; ++j) {
        float vm = fmaxf(fmaxf(fmaxf(acc[p][0][j], acc[p][1][j]),
                               fmaxf(acc[p][2][j], acc[p][3][j])), 0.f);
        atomicMax(&om[c4[p] + j], __float_as_uint(vm));
      }
    } else {
#pragma unroll
      for (int i = 0; i < 4; ++i)
#pragma unroll
        for (int j = 0; j < 4; ++j)
          hout[(s4[p] + i) * C + c4[p] + j] = fmaxf(acc[p][i][j], 0.f);
    }
  }
}

// ---------------------------------------------------------------- MLP (SA1)
__global__ __launch_bounds__(256) void k_mlp1(const float* __restrict__ g1,
    const float* __restrict__ w0, const float* __restrict__ b0,
    const float* __restrict__ w1, const float* __restrict__ b1,
    const float* __restrict__ w2, const float* __restrict__ b2,
    float* __restrict__ l1f) {
  const int t = threadIdx.x;
  const int b = blockIdx.x & 31, m = blockIdx.x >> 5;
  __shared__ __align__(16) float h0[32 * 4];
  __shared__ __align__(16) float h1[32 * 64];
  __shared__ __align__(16) float h2[32 * 64];
  __shared__ __align__(16) float wst[16 * 128];
  __shared__ unsigned om[128];
  const float* gi = g1 + ((size_t)(b * NP1 + m)) * NS1 * 3;
  if (t < 96) h0[(t / 3) * 4 + (t % 3)] = gi[t];
  if (t < 128) om[t] = 0u;
  __syncthreads();
  sa_layer<3, 64, 1>(w0, b0, h0, 4, h1, nullptr, wst, t);
  sa_layer<64, 64, 1>(w1, b1, h1, 64, h2, nullptr, wst, t);
  sa_layer<64, 128, 1>(w2, b2, h2, 64, nullptr, om, wst, t);
  __syncthreads();
  if (t < 128) l1f[((size_t)(b * NP1 + m)) * 128 + t] = __uint_as_float(om[t]);
}

// ---------------------------------------------------------------- FPS (SA2)
__global__ __launch_bounds__(128) void k_fps2(const float* __restrict__ l1x,
                                              float* __restrict__ l2x) {
  const int b = blockIdx.x, t = threadIdx.x;  // 128 threads
  const float* xb = l1x + (size_t)b * NP1 * 3;
  float px = xb[t * 3], py = xb[t * 3 + 1], pz = xb[t * 3 + 2];
  float dd = 1e10f;
  __shared__ float swv[2]; __shared__ int swi[2];
  __shared__ float s_cx, s_cy, s_cz; __shared__ int s_far;
  if (t == 0) { s_cx = xb[0]; s_cy = xb[1]; s_cz = xb[2]; }
  __syncthreads();
  for (int it = 0; it < NP2; ++it) {
    float cx = s_cx, cy = s_cy, cz = s_cz;
    if (t == 0) {
      float* o = l2x + ((size_t)b * NP2 + it) * 3;
      o[0] = cx; o[1] = cy; o[2] = cz;
    }
    float dx = px - cx, dy = py - cy, dz = pz - cz;
    dd = fminf(dd, dx * dx + dy * dy + dz * dz);
    float bd = dd; int bi = t;
#pragma unroll
    for (int off = 32; off > 0; off >>= 1) {
      float od = __shfl_down(bd, off); int oi = __shfl_down(bi, off);
      if (od > bd || (od == bd && oi < bi)) { bd = od; bi = oi; }
    }
    if ((t & 63) == 0) { swv[t >> 6] = bd; swi[t >> 6] = bi; }
    __syncthreads();
    if (t == 0) {
      if (swv[1] > bd || (swv[1] == bd && swi[1] < bi)) bi = swi[1];
      s_far = bi;
    }
    __syncthreads();
    if (t == s_far) { s_cx = px; s_cy = py; s_cz = pz; }
    __syncthreads();
  }
}

// ---------------------------------------------------------------- kNN (SA2)
__global__ __launch_bounds__(256) void k_knn2(const float* __restrict__ l1x,
                                              const float* __restrict__ l2x,
                                              int* __restrict__ nidx2) {
  const int b = blockIdx.x, t = threadIdx.x;
  const int lane = t & 63, wv = t >> 6;
  __shared__ float pxs[128], pys[128], pzs[128];
  if (t < 128) {
    pxs[t] = l1x[((size_t)b * NP1 + t) * 3 + 0];
    pys[t] = l1x[((size_t)b * NP1 + t) * 3 + 1];
    pzs[t] = l1x[((size_t)b * NP1 + t) * 3 + 2];
  }
  __syncthreads();
  for (int mc = wv; mc < NP2; mc += 4) {
    const float* cp = l2x + ((size_t)b * NP2 + mc) * 3;
    float cx = cp[0], cy = cp[1], cz = cp[2];
    float dx = pxs[lane] - cx, dy = pys[lane] - cy, dz = pzs[lane] - cz;
    float d0 = dx * dx + dy * dy + dz * dz;
    dx = pxs[lane + 64] - cx; dy = pys[lane + 64] - cy; dz = pzs[lane + 64] - cz;
    float d1 = dx * dx + dy * dy + dz * dz;
    int* no = nidx2 + ((size_t)b * NP2 + mc) * NS2;
    for (int it = 0; it < NS2; ++it) {
      float bv; int bi;
      if (d1 < d0) { bv = d1; bi = lane + 64; } else { bv = d0; bi = lane; }
#pragma unroll
      for (int off = 32; off > 0; off >>= 1) {
        float ov = __shfl_down(bv, off); int oi = __shfl_down(bi, off);
        if (ov < bv || (ov == bv && oi < bi)) { bv = ov; bi = oi; }
      }
      bi = __shfl(bi, 0);
      if (lane == (bi & 63)) { if (bi < 64) d0 = 1e30f; else d1 = 1e30f; }
      if (lane == 0) no[it] = bi;
    }
  }
}

// ---------------------------------------------------------------- MLP (SA2)
__global__ __launch_bounds__(256) void k_mlp2(const float* __restrict__ l1x,
    const float* __restrict__ l2x, const float* __restrict__ l1f,
    const int* __restrict__ nidx2,
    const float* __restrict__ w0, const float* __restrict__ b0,
    const float* __restrict__ w1, const float* __restrict__ b1,
    const float* __restrict__ w2, const float* __restrict__ b2,
    float* __restrict__ l2f) {
  const int t = threadIdx.x;
  const int b = blockIdx.x & 31, mc = blockIdx.x >> 5;
  __shared__ __align__(16) float h0[32 * 132];  // reused as h2 (32x128) after L1
  __shared__ __align__(16) float h1[32 * 128];
  __shared__ __align__(16) float wst[16 * 256];
  __shared__ unsigned om[256];
  __shared__ int sni[32];
  if (t < 32) sni[t] = nidx2[((size_t)b * NP2 + mc) * NS2 + t];
  om[t] = 0u;
  __syncthreads();
  const float* l1fb = l1f + (size_t)b * NP1 * 128;
  for (int i = t; i < 32 * 128; i += 256) {
    int r = i >> 7, cc = i & 127;
    h0[r * 132 + 3 + cc] = l1fb[(size_t)sni[r] * 128 + cc];
  }
  if (t < 96) {
    int r = t / 3, ax = t - 3 * r;
    h0[r * 132 + ax] = l1x[((size_t)b * NP1 + sni[r]) * 3 + ax] -
                       l2x[((size_t)b * NP2 + mc) * 3 + ax];
  }
  __syncthreads();
  sa_layer<131, 128, 1>(w0, b0, h0, 132, h1, nullptr, wst, t);
  sa_layer<128, 128, 1>(w1, b1, h1, 128, h0, nullptr, wst, t);  // h2 := h0
  sa_layer<128, 256, 2>(w2, b2, h0, 128, nullptr, om, wst, t);
  __syncthreads();
  l2f[((size_t)(b * NP2 + mc)) * 256 + t] = __uint_as_float(om[t]);
}

// ------------------------------------------------------------- MLP (SA3, group_all)
__global__ __launch_bounds__(512) void k_mlp3(const float* __restrict__ l2x,
    const float* __restrict__ l2f,
    const float* __restrict__ w0, const float* __restrict__ b0,
    const float* __restrict__ w1, const float* __restrict__ b1,
    const float* __restrict__ w2, const float* __restrict__ b2,
    float* __restrict__ l3f) {
  const int t = threadIdx.x;
  const int b = blockIdx.x & 31, sg = blockIdx.x >> 5;  // 8 groups x 4 samples
  __shared__ float in[4][260];
  __shared__ float h1[4][256];
  __shared__ float h2[4][512];
  for (int i = t; i < 4 * 256; i += 512) {
    int s = i >> 8, c = i & 255;
    in[s][3 + c] = l2f[((size_t)(b * NP2) + sg * 4 + s) * 256 + c];
  }
  if (t < 12) {
    int s = t / 3, ax = t - 3 * s;
    in[s][ax] = l2x[((size_t)b * NP2 + sg * 4 + s) * 3 + ax];
  }
  __syncthreads();
  if (t < 256) {  // L1: 259 -> 256
    float a0 = b0[t], a1 = a0, a2 = a0, a3 = a0;
    for (int k = 0; k < 259; ++k) {
      float w = w0[k * 256 + t];
      a0 += in[0][k] * w; a1 += in[1][k] * w; a2 += in[2][k] * w; a3 += in[3][k] * w;
    }
    h1[0][t] = fmaxf(a0, 0.f); h1[1][t] = fmaxf(a1, 0.f);
    h1[2][t] = fmaxf(a2, 0.f); h1[3][t] = fmaxf(a3, 0.f);
  }
  __syncthreads();
  {  // L2: 256 -> 512
    float a0 = b1[t], a1 = a0, a2 = a0, a3 = a0;
    for (int k = 0; k < 256; ++k) {
      float w = w1[k * 512 + t];
      a0 += h1[0][k] * w; a1 += h1[1][k] * w; a2 += h1[2][k] * w; a3 += h1[3][k] * w;
    }
    h2[0][t] = fmaxf(a0, 0.f); h2[1][t] = fmaxf(a1, 0.f);
    h2[2][t] = fmaxf(a2, 0.f); h2[3][t] = fmaxf(a3, 0.f);
  }
  __syncthreads();
  {  // L3: 512 -> 1024, maxpool over 4 samples, global atomic max over groups
    float a[2][4];
#pragma unroll
    for (int p = 0; p < 2; ++p) {
      float bv = b2[t + p * 512];
      a[p][0] = bv; a[p][1] = bv; a[p][2] = bv; a[p][3] = bv;
    }
    for (int k = 0; k < 512; ++k) {
      float x0 = h2[0][k], x1 = h2[1][k], x2 = h2[2][k], x3 = h2[3][k];
      float wA = w2[k * 1024 + t];
      float wB = w2[k * 1024 + t + 512];
      a[0][0] += x0 * wA; a[0][1] += x1 * wA; a[0][2] += x2 * wA; a[0][3] += x3 * wA;
      a[1][0] += x0 * wB; a[1][1] += x1 * wB; a[1][2] += x2 * wB; a[1][3] += x3 * wB;
    }
#pragma unroll
    for (int p = 0; p < 2; ++p) {
      float vm = fmaxf(fmaxf(fmaxf(a[p][0], a[p][1]), fmaxf(a[p][2], a[p][3])), 0.f);
      atomicMax((unsigned*)l3f + (size_t)b * 1024 + t + p * 512, __float_as_uint(vm));
    }
  }
}

// ---------------------------------------------------------------- FC head
__global__ __launch_bounds__(256) void k_head(const float* __restrict__ l3f,
    const float* __restrict__ fc1w, const float* __restrict__ fc1b,
    const float* __restrict__ lg1, const float* __restrict__ lb1,
    const float* __restrict__ fc2w, const float* __restrict__ fc2b,
    const float* __restrict__ lg2, const float* __restrict__ lb2,
    const float* __restrict__ piw, const float* __restrict__ pib,
    const float* __restrict__ muw, const float* __restrict__ mub,
    const float* __restrict__ kw, const float* __restrict__ kb,
    float* __restrict__ out) {
  const int b = blockIdx.x, t = threadIdx.x;
  __shared__ float x[1024], x1[512], x2[256];
  __shared__ float red[8];
  __shared__ float hv[16];
  for (int i = t; i < 1024; i += 256) x[i] = l3f[(size_t)b * 1024 + i];
  __syncthreads();
  // fc1 (1024 -> 512), 2 outputs/thread
  float a0 = fc1b[t], a1 = fc1b[t + 256];
  for (int k = 0; k < 1024; ++k) {
    float xv = x[k];
    a0 += xv * fc1w[k * 512 + t];
    a1 += xv * fc1w[k * 512 + t + 256];
  }
  {  // LN1 (biased var) + relu
    float s = a0 + a1, ss = a0 * a0 + a1 * a1;
#pragma unroll
    for (int off = 32; off > 0; off >>= 1) { s += __shfl_down(s, off); ss += __shfl_down(ss, off); }
    if ((t & 63) == 0) { red[t >> 6] = s; red[4 + (t >> 6)] = ss; }
    __syncthreads();
    if (t == 0) {
      float S = red[0] + red[1] + red[2] + red[3];
      float SS = red[4] + red[5] + red[6] + red[7];
      float mean = S / 512.f;
      red[0] = mean; red[4] = SS / 512.f - mean * mean;
    }
    __syncthreads();
    float mean = red[0], var = red[4];
    float rs = rsqrtf(var + 1e-5f);
    x1[t]       = fmaxf((a0 - mean) * rs * lg1[t] + lb1[t], 0.f);
    x1[t + 256] = fmaxf((a1 - mean) * rs * lg1[t + 256] + lb1[t + 256], 0.f);
  }
  __syncthreads();
  // fc2 (512 -> 256)
  float a = fc2b[t];
  for (int k = 0; k < 512; ++k) a += x1[k] * fc2w[k * 256 + t];
  {  // LN2 + relu
    float s = a, ss = a * a;
#pragma unroll
    for (int off = 32; off > 0; off >>= 1) { s += __shfl_down(s, off); ss += __shfl_down(ss, off); }
    if ((t & 63) == 0) { red[t >> 6] = s; red[4 + (t >> 6)] = ss; }
    __syncthreads();
    if (t == 0) {
      float S = red[0] + red[1] + red[2] + red[3];
      float SS = red[4] + red[5] + red[6] + red[7];
      float mean = S / 256.f;
      red[0] = mean; red[4] = SS / 256.f - mean * mean;
    }
    __syncthreads();
    float mean = red[0], var = red[4];
    x2[t] = fmaxf((a - mean) * rsqrtf(var + 1e-5f) * lg2[t] + lb2[t], 0.f);
  }
  __syncthreads();
  // heads: 16 dot products over 256
  if (t < 16) {
    const float* W; const float* bb; int c; int C;
    if (t < 4)        { W = piw; bb = pib; c = t;      C = 4; }
    else if (t < 12)  { W = muw; bb = mub; c = t - 4;  C = 8; }
    else              { W = kw;  bb = kb;  c = t - 12; C = 4; }
    float acc = bb[c];
    for (int k = 0; k < 256; ++k) acc += x2[k] * W[k * C + c];
    hv[t] = acc;
  }
  __syncthreads();
  if (t == 0) {
    // softmax((pi)/0.7)
    float z[4], mx = -1e30f;
#pragma unroll
    for (int i = 0; i < 4; ++i) { z[i] = hv[i] / 0.7f; mx = fmaxf(mx, z[i]); }
    float e[4], sum = 0.f;
#pragma unroll
    for (int i = 0; i < 4; ++i) { e[i] = expf(z[i] - mx); sum += e[i]; }
#pragma unroll
    for (int k = 0; k < 4; ++k) {
      // mu
      float c0 = hv[4 + 2 * k], s0 = hv[4 + 2 * k + 1];
      float nr = sqrtf(c0 * c0 + s0 * s0);
      float den = fmaxf(nr, 1e-4f);
      float cu = c0 / den, su = s0 / den;
      float n2 = sqrtf(cu * cu + su * su);
      if (n2 < 1e-3f) { cu = 1.f; su = 0.f; }
      out[b * 4 + k] = atan2f(su, cu);
      // kappa
      float zk = hv[12 + k];
      float sp = fmaxf(zk, 0.f) + log1pf(expf(-fabsf(zk)));
      out[128 + b * 4 + k] = fminf(sp + 1e-6f, 80.f);
      // weight
      out[256 + b * 4 + k] = e[k] / sum;
    }
  }
}

// ---------------------------------------------------------------- launch
extern "C" void kernel_launch(void* const* d_in, const int* in_sizes, int n_in,
                              void* d_out, int out_size, void* d_ws, size_t ws_size,
                              hipStream_t stream) {
  const float* xyz  = (const float*)d_in[0];
  const float* s1w0 = (const float*)d_in[1];  const float* s1b0 = (const float*)d_in[2];
  const float* s1w1 = (const float*)d_in[3];  const float* s1b1 = (const float*)d_in[4];
  const float* s1w2 = (const float*)d_in[5];  const float* s1b2 = (const float*)d_in[6];
  const float* s2w0 = (const float*)d_in[7];  const float* s2b0 = (const float*)d_in[8];
  const float* s2w1 = (const float*)d_in[9];  const float* s2b1 = (const float*)d_in[10];
  const float* s2w2 = (const float*)d_in[11]; const float* s2b2 = (const float*)d_in[12];
  const float* s3w0 = (const float*)d_in[13]; const float* s3b0 = (const float*)d_in[14];
  const float* s3w1 = (const float*)d_in[15]; const float* s3b1 = (const float*)d_in[16];
  const float* s3w2 = (const float*)d_in[17]; const float* s3b2 = (const float*)d_in[18];
  const float* fc1w = (const float*)d_in[19]; const float* fc1b = (const float*)d_in[20];
  const float* lg1  = (const float*)d_in[21]; const float* lb1  = (const float*)d_in[22];
  const float* fc2w = (const float*)d_in[23]; const float* fc2b = (const float*)d_in[24];
  const float* lg2  = (const float*)d_in[25]; const float* lb2  = (const float*)d_in[26];
  const float* piw  = (const float*)d_in[27]; const float* pib  = (const float*)d_in[28];
  const float* muw  = (const float*)d_in[29]; const float* mub  = (const float*)d_in[30];
  const float* kw   = (const float*)d_in[31]; const float* kb   = (const float*)d_in[32];

  float* ws   = (float*)d_ws;
  float* l1x  = ws + OFF_L1X;
  float* g1   = ws + OFF_G1;
  float* l1f  = ws + OFF_L1F;
  float* l2x  = ws + OFF_L2X;
  int*   nid2 = (int*)(ws + OFF_NIDX2);
  float* l2f  = ws + OFF_L2F;
  float* l3f  = ws + OFF_L3F;
  float* out  = (float*)d_out;

  hipMemsetAsync(l3f, 0, (size_t)B * 1024 * sizeof(float), stream);
  k_fps1<<<B, 1024, 0, stream>>>(xyz, l1x);
  k_knn1<<<B * NP1, 256, 0, stream>>>(xyz, l1x, g1);
  k_mlp1<<<B * NP1, 256, 0, stream>>>(g1, s1w0, s1b0, s1w1, s1b1, s1w2, s1b2, l1f);
  k_fps2<<<B, 128, 0, stream>>>(l1x, l2x);
  k_knn2<<<B, 256, 0, stream>>>(l1x, l2x, nid2);
  k_mlp2<<<B * NP2, 256, 0, stream>>>(l1x, l2x, l1f, nid2,
                                      s2w0, s2b0, s2w1, s2b1, s2w2, s2b2, l2f);
  k_mlp3<<<B * 8, 512, 0, stream>>>(l2x, l2f, s3w0, s3b0, s3w1, s3b1, s3w2, s3b2, l3f);
  k_head<<<B, 256, 0, stream>>>(l3f, fc1w, fc1b, lg1, lb1, fc2w, fc2b, lg2, lb2,
                                piw, pib, muw, mub, kw, kb, out);
}

// Round 5
// 930.532 us; speedup vs baseline: 1.0151x; 1.0151x over previous
//
#include <hip/hip_runtime.h>
#include <math.h>

#define B 32
#define N1 16384
#define NP1 128
#define NS1 32
#define NP2 32
#define NS2 32

// workspace offsets (in floats)
#define OFF_L1X   0
#define OFF_G1    12288
#define OFF_L1F   405504
#define OFF_L2X   929792
#define OFF_NIDX2 932864
#define OFF_L2F   965632
#define OFF_L3F   1227776

// ---------------------------------------------------------------- FPS (SA1)
// One barrier per round; per-wave winners in 16 double-buffered LDS slots.
// __launch_bounds__(1024, 4): 16 waves/block = 4 waves/SIMD -> VGPR budget
// 128/wave, so the 64 resident floats (px/py/pz/dd) stay in registers.
// (R2/R3 showed VGPR_Count=48: default occupancy target made the compiler
// spill the point cloud to scratch, re-read every one of the 128 rounds.)
__global__ __launch_bounds__(1024, 4) void k_fps1(const float* __restrict__ xyz,
                                                  float* __restrict__ l1x) {
  const int b = blockIdx.x, t = threadIdx.x;
  const float* xb = xyz + (size_t)b * N1 * 3;
  float px[16], py[16], pz[16], dd[16];
#pragma unroll
  for (int j = 0; j < 16; ++j) {
    int idx = t + (j << 10);
    px[j] = xb[idx * 3 + 0]; py[j] = xb[idx * 3 + 1]; pz[j] = xb[idx * 3 + 2];
    dd[j] = 1e10f;
  }
  __shared__ unsigned long long slots[2][16];
  if (t < 16) slots[0][t] = (t == 0) ? 0xFFFFFFFFull : 0ull;  // round-0 winner: idx 0
  __syncthreads();
  for (int it = 0; it < NP1; ++it) {
    // winner of previous round = max over 16 slots (broadcast LDS reads)
    unsigned long long key = slots[it & 1][0];
#pragma unroll
    for (int w = 1; w < 16; ++w) {
      unsigned long long k2 = slots[it & 1][w];
      if (k2 > key) key = k2;
    }
    const int widx = (int)(0xFFFFFFFFu - (unsigned)(key & 0xFFFFFFFFull));
    const float cx = xb[widx * 3 + 0];   // wave-uniform broadcast load (L2-hot)
    const float cy = xb[widx * 3 + 1];
    const float cz = xb[widx * 3 + 2];
    if (t == 0) {
      float* o = l1x + ((size_t)b * NP1 + it) * 3;
      o[0] = cx; o[1] = cy; o[2] = cz;
    }
    // update running min-dist, thread-local argmax (j ascending => lowest idx)
    float bd = -1.f; int bj = 0;
#pragma unroll
    for (int j = 0; j < 16; ++j) {
      float dx = px[j] - cx, dy = py[j] - cy, dz = pz[j] - cz;
      float d = dx * dx + dy * dy + dz * dz;
      float nd = fminf(dd[j], d);
      dd[j] = nd;
      if (nd > bd) { bd = nd; bj = j; }
    }
    unsigned long long mykey =
        ((unsigned long long)__float_as_uint(bd) << 32) |
        (unsigned long long)(0xFFFFFFFFu - (unsigned)(t + (bj << 10)));
#pragma unroll
    for (int off = 32; off > 0; off >>= 1) {
      unsigned long long ok = __shfl_down(mykey, off);
      if (ok > mykey) mykey = ok;
    }
    if ((t & 63) == 0) slots[(it + 1) & 1][t >> 6] = mykey;
    __syncthreads();   // publishes slots for round it+1; done with slots[it&1]
  }
}

// ---------------------------------------------------------------- kNN (SA1)
// Histogram-select on float-bit bins + parallel exact ranking. ~6 barriers
// total (vs ~130 serial extract-min barriers in the round-0 version).
__device__ __forceinline__ float dist3(const float* __restrict__ xb, int idx,
                                       float cx, float cy, float cz,
                                       float& x, float& y, float& z) {
  x = xb[idx * 3 + 0]; y = xb[idx * 3 + 1]; z = xb[idx * 3 + 2];
  float dx = x - cx, dy = y - cy, dz = z - cz;
  return dx * dx + dy * dy + dz * dz;
}

#define KNN_CAP 512
#define NBIN 2048

__global__ __launch_bounds__(256) void k_knn1(const float* __restrict__ xyz,
                                              const float* __restrict__ l1x,
                                              float* __restrict__ g1) {
  const int t = threadIdx.x;
  const int b = blockIdx.x & 31;       // keeps same-batch blocks on one XCD
  const int m = blockIdx.x >> 5;
  const float* xb = xyz + (size_t)b * N1 * 3;
  const float* cp = l1x + ((size_t)b * NP1 + m) * 3;
  const float cx = cp[0], cy = cp[1], cz = cp[2];

  __shared__ int hist[NBIN];
  __shared__ float cd[KNN_CAP]; __shared__ int ci[KNN_CAP];
  __shared__ float cpx[KNN_CAP], cpy[KNN_CAP], cpz[KNN_CAP];
  __shared__ int s_cnt, s_cut;
  __shared__ int wsum[4];

  for (int i = t; i < NBIN; i += 256) hist[i] = 0;
  if (t == 0) { s_cnt = 0; s_cut = NBIN - 1; }
  __syncthreads();

  // pass 1: histogram of monotone float-bit bins (d >= 0 so bits are monotone)
  for (int j = 0; j < 64; ++j) {
    float x, y, z;
    float d = dist3(xb, t + (j << 8), cx, cy, cz, x, y, z);
    atomicAdd(&hist[__float_as_uint(d) >> 20], 1);
  }
  __syncthreads();

  // find cutoff bin: smallest bin with cumulative count >= 32
  {
    int loc = 0;
#pragma unroll
    for (int j = 0; j < 8; ++j) loc += hist[t * 8 + j];
    int v = loc;
#pragma unroll
    for (int off = 1; off < 64; off <<= 1) {
      int u = __shfl_up(v, off);
      if ((t & 63) >= off) v += u;
    }
    if ((t & 63) == 63) wsum[t >> 6] = v;
    __syncthreads();
    int woff = 0;
    for (int w = 0; w < (t >> 6); ++w) woff += wsum[w];
    int incl = v + woff, excl = incl - loc;
    if (excl < NS1 && incl >= NS1) {  // exactly one thread
      int c = excl;
#pragma unroll
      for (int j = 0; j < 8; ++j) {
        c += hist[t * 8 + j];
        if (c >= NS1) { s_cut = t * 8 + j; break; }
      }
    }
  }
  __syncthreads();
  const unsigned cut = (unsigned)s_cut + 1u;  // +1 bin slack vs recompute drift

  // pass 2: collect candidates (cumulative count through cutoff >= 32)
  for (int j = 0; j < 64; ++j) {
    float x, y, z;
    float d = dist3(xb, t + (j << 8), cx, cy, cz, x, y, z);
    if ((__float_as_uint(d) >> 20) <= cut) {
      int p = atomicAdd(&s_cnt, 1);
      if (p < KNN_CAP) { cd[p] = d; ci[p] = t + (j << 8); cpx[p] = x; cpy[p] = y; cpz[p] = z; }
    }
  }
  __syncthreads();
  const int cnt = (s_cnt < KNN_CAP) ? s_cnt : KNN_CAP;

  // exact lexicographic (d, idx) ranking — fully parallel, no serial rounds
  float* gout = g1 + ((size_t)(b * NP1 + m)) * NS1 * 3;
  for (int p = t; p < cnt; p += 256) {
    const float dp = cd[p]; const int ip = ci[p];
    int rank = 0;
    for (int q = 0; q < cnt; ++q) {
      float dq = cd[q];
      rank += (dq < dp || (dq == dp && ci[q] < ip)) ? 1 : 0;
    }
    if (rank < NS1) {
      gout[rank * 3 + 0] = cpx[p] - cx;
      gout[rank * 3 + 1] = cpy[p] - cy;
      gout[rank * 3 + 2] = cpz[p] - cz;
    }
  }
}

// ------------------------------------------------- generic SA-MLP layer (S=32)
// 4s x 4c register tiles, weights LDS-staged in 16-row chunks.
template <int K, int C, int TPT>
__device__ __forceinline__ void sa_layer(const float* __restrict__ W,
                                         const float* __restrict__ bias,
                                         const float* __restrict__ hin, int instride,
                                         float* __restrict__ hout,
                                         unsigned* __restrict__ om,
                                         float* __restrict__ wst, int t) {
  constexpr int CT = C / 4;
  constexpr int NT = 8 * CT;  // (32/4) s-tiles * c-tiles
  float acc[TPT][4][4];
  int s4[TPT], c4[TPT]; bool on[TPT];
#pragma unroll
  for (int p = 0; p < TPT; ++p) {
    int tile = t + p * 256;
    on[p] = tile < NT;
    int tl = on[p] ? tile : 0;
    s4[p] = (tl / CT) * 4; c4[p] = (tl % CT) * 4;
    float4 bb = *(const float4*)(bias + c4[p]);
#pragma unroll
    for (int i = 0; i < 4; ++i) {
      acc[p][i][0] = bb.x; acc[p][i][1] = bb.y; acc[p][i][2] = bb.z; acc[p][i][3] = bb.w;
    }
  }
  for (int k0 = 0; k0 < K; k0 += 16) {
    const int kc = (K - k0 < 16) ? (K - k0) : 16;
    __syncthreads();
    for (int i = t; i < kc * C; i += 256) wst[i] = W[k0 * C + i];
    __syncthreads();
    if (kc == 16) {
#pragma unroll
      for (int kk = 0; kk < 16; ++kk) {
#pragma unroll
        for (int p = 0; p < TPT; ++p) {
          float4 w = *(const float4*)(wst + kk * C + c4[p]);
#pragma unroll
          for (int i = 0; i < 4; ++i) {
            float a = hin[(s4[p] + i) * instride + (k0 + kk)];
            acc[p][i][0] += a * w.x; acc[p][i][1] += a * w.y;
            acc[p][i][2] += a * w.z; acc[p][i][3] += a * w.w;
          }
        }
      }
    } else {
      for (int kk = 0; kk < kc; ++kk) {
#pragma unroll
        for (int p = 0; p < TPT; ++p) {
          float4 w = *(const float4*)(wst + kk * C + c4[p]);
#pragma unroll
          for (int i = 0; i < 4; ++i) {
            float a = hin[(s4[p] + i) * instride + (k0 + kk)];
            acc[p][i][0] += a * w.x; acc[p][i][1] += a * w.y;
            acc[p][i][2] += a * w.z; acc[p][i][3] += a * w.w;
          }
        }
      }
    }
  }
#pragma unroll
  for (int p = 0; p < TPT; ++p) {
    if (!on[p]) continue;
    if (om) {
#pragma unroll
      for (int j = 0; j < 4; ++j) {
        float vm = fmaxf(fmaxf(fmaxf(acc[p][0][j], acc[p][1][j]),
                               fmaxf(acc[p][2][j], acc[p][3][j])), 0.f);
        atomicMax(&om[c4[p] + j], __float_as_uint(vm));
      }
    } else {
#pragma unroll
      for (int i = 0; i < 4; ++i)
#pragma unroll
        for (int j = 0; j < 4; ++j)
          hout[(s4[p] + i) * C + c4[p] + j] = fmaxf(acc[p][i][j], 0.f);
    }
  }
}

// ---------------------------------------------------------------- MLP (SA1)
__global__ __launch_bounds__(256) void k_mlp1(const float* __restrict__ g1,
    const float* __restrict__ w0, const float* __restrict__ b0,
    const float* __restrict__ w1, const float* __restrict__ b1,
    const float* __restrict__ w2, const float* __restrict__ b2,
    float* __restrict__ l1f) {
  const int t = threadIdx.x;
  const int b = blockIdx.x & 31, m = blockIdx.x >> 5;
  __shared__ __align__(16) float h0[32 * 4];
  __shared__ __align__(16) float h1[32 * 64];
  __shared__ __align__(16) float h2[32 * 64];
  __shared__ __align__(16) float wst[16 * 128];
  __shared__ unsigned om[128];
  const float* gi = g1 + ((size_t)(b * NP1 + m)) * NS1 * 3;
  if (t < 96) h0[(t / 3) * 4 + (t % 3)] = gi[t];
  if (t < 128) om[t] = 0u;
  __syncthreads();
  sa_layer<3, 64, 1>(w0, b0, h0, 4, h1, nullptr, wst, t);
  sa_layer<64, 64, 1>(w1, b1, h1, 64, h2, nullptr, wst, t);
  sa_layer<64, 128, 1>(w2, b2, h2, 64, nullptr, om, wst, t);
  __syncthreads();
  if (t < 128) l1f[((size_t)(b * NP1 + m)) * 128 + t] = __uint_as_float(om[t]);
}

// ---------------------------------------------------------------- FPS (SA2)
__global__ __launch_bounds__(128) void k_fps2(const float* __restrict__ l1x,
                                              float* __restrict__ l2x) {
  const int b = blockIdx.x, t = threadIdx.x;  // 128 threads
  const float* xb = l1x + (size_t)b * NP1 * 3;
  float px = xb[t * 3], py = xb[t * 3 + 1], pz = xb[t * 3 + 2];
  float dd = 1e10f;
  __shared__ float swv[2]; __shared__ int swi[2];
  __shared__ float s_cx, s_cy, s_cz; __shared__ int s_far;
  if (t == 0) { s_cx = xb[0]; s_cy = xb[1]; s_cz = xb[2]; }
  __syncthreads();
  for (int it = 0; it < NP2; ++it) {
    float cx = s_cx, cy = s_cy, cz = s_cz;
    if (t == 0) {
      float* o = l2x + ((size_t)b * NP2 + it) * 3;
      o[0] = cx; o[1] = cy; o[2] = cz;
    }
    float dx = px - cx, dy = py - cy, dz = pz - cz;
    dd = fminf(dd, dx * dx + dy * dy + dz * dz);
    float bd = dd; int bi = t;
#pragma unroll
    for (int off = 32; off > 0; off >>= 1) {
      float od = __shfl_down(bd, off); int oi = __shfl_down(bi, off);
      if (od > bd || (od == bd && oi < bi)) { bd = od; bi = oi; }
    }
    if ((t & 63) == 0) { swv[t >> 6] = bd; swi[t >> 6] = bi; }
    __syncthreads();
    if (t == 0) {
      if (swv[1] > bd || (swv[1] == bd && swi[1] < bi)) bi = swi[1];
      s_far = bi;
    }
    __syncthreads();
    if (t == s_far) { s_cx = px; s_cy = py; s_cz = pz; }
    __syncthreads();
  }
}

// ---------------------------------------------------------------- kNN (SA2)
__global__ __launch_bounds__(256) void k_knn2(const float* __restrict__ l1x,
                                              const float* __restrict__ l2x,
                                              int* __restrict__ nidx2) {
  const int b = blockIdx.x, t = threadIdx.x;
  const int lane = t & 63, wv = t >> 6;
  __shared__ float pxs[128], pys[128], pzs[128];
  if (t < 128) {
    pxs[t] = l1x[((size_t)b * NP1 + t) * 3 + 0];
    pys[t] = l1x[((size_t)b * NP1 + t) * 3 + 1];
    pzs[t] = l1x[((size_t)b * NP1 + t) * 3 + 2];
  }
  __syncthreads();
  for (int mc = wv; mc < NP2; mc += 4) {
    const float* cp = l2x + ((size_t)b * NP2 + mc) * 3;
    float cx = cp[0], cy = cp[1], cz = cp[2];
    float dx = pxs[lane] - cx, dy = pys[lane] - cy, dz = pzs[lane] - cz;
    float d0 = dx * dx + dy * dy + dz * dz;
    dx = pxs[lane + 64] - cx; dy = pys[lane + 64] - cy; dz = pzs[lane + 64] - cz;
    float d1 = dx * dx + dy * dy + dz * dz;
    int* no = nidx2 + ((size_t)b * NP2 + mc) * NS2;
    for (int it = 0; it < NS2; ++it) {
      float bv; int bi;
      if (d1 < d0) { bv = d1; bi = lane + 64; } else { bv = d0; bi = lane; }
#pragma unroll
      for (int off = 32; off > 0; off >>= 1) {
        float ov = __shfl_down(bv, off); int oi = __shfl_down(bi, off);
        if (ov < bv || (ov == bv && oi < bi)) { bv = ov; bi = oi; }
      }
      bi = __shfl(bi, 0);
      if (lane == (bi & 63)) { if (bi < 64) d0 = 1e30f; else d1 = 1e30f; }
      if (lane == 0) no[it] = bi;
    }
  }
}

// ---------------------------------------------------------------- MLP (SA2)
__global__ __launch_bounds__(256) void k_mlp2(const float* __restrict__ l1x,
    const float* __restrict__ l2x, const float* __restrict__ l1f,
    const int* __restrict__ nidx2,
    const float* __restrict__ w0, const float* __restrict__ b0,
    const float* __restrict__ w1, const float* __restrict__ b1,
    const float* __restrict__ w2, const float* __restrict__ b2,
    float* __restrict__ l2f) {
  const int t = threadIdx.x;
  const int b = blockIdx.x & 31, mc = blockIdx.x >> 5;
  __shared__ __align__(16) float h0[32 * 132];  // reused as h2 (32x128) after L1
  __shared__ __align__(16) float h1[32 * 128];
  __shared__ __align__(16) float wst[16 * 256];
  __shared__ unsigned om[256];
  __shared__ int sni[32];
  if (t < 32) sni[t] = nidx2[((size_t)b * NP2 + mc) * NS2 + t];
  om[t] = 0u;
  __syncthreads();
  const float* l1fb = l1f + (size_t)b * NP1 * 128;
  for (int i = t; i < 32 * 128; i += 256) {
    int r = i >> 7, cc = i & 127;
    h0[r * 132 + 3 + cc] = l1fb[(size_t)sni[r] * 128 + cc];
  }
  if (t < 96) {
    int r = t / 3, ax = t - 3 * r;
    h0[r * 132 + ax] = l1x[((size_t)b * NP1 + sni[r]) * 3 + ax] -
                       l2x[((size_t)b * NP2 + mc) * 3 + ax];
  }
  __syncthreads();
  sa_layer<131, 128, 1>(w0, b0, h0, 132, h1, nullptr, wst, t);
  sa_layer<128, 128, 1>(w1, b1, h1, 128, h0, nullptr, wst, t);  // h2 := h0
  sa_layer<128, 256, 2>(w2, b2, h0, 128, nullptr, om, wst, t);
  __syncthreads();
  l2f[((size_t)(b * NP2 + mc)) * 256 + t] = __uint_as_float(om[t]);
}

// ------------------------------------------------------------- MLP (SA3, group_all)
__global__ __launch_bounds__(512) void k_mlp3(const float* __restrict__ l2x,
    const float* __restrict__ l2f,
    const float* __restrict__ w0, const float* __restrict__ b0,
    const float* __restrict__ w1, const float* __restrict__ b1,
    const float* __restrict__ w2, const float* __restrict__ b2,
    float* __restrict__ l3f) {
  const int t = threadIdx.x;
  const int b = blockIdx.x & 31, sg = blockIdx.x >> 5;  // 8 groups x 4 samples
  __shared__ float in[4][260];
  __shared__ float h1[4][256];
  __shared__ float h2[4][512];
  for (int i = t; i < 4 * 256; i += 512) {
    int s = i >> 8, c = i & 255;
    in[s][3 + c] = l2f[((size_t)(b * NP2) + sg * 4 + s) * 256 + c];
  }
  if (t < 12) {
    int s = t / 3, ax = t - 3 * s;
    in[s][ax] = l2x[((size_t)b * NP2 + sg * 4 + s) * 3 + ax];
  }
  __syncthreads();
  if (t < 256) {  // L1: 259 -> 256
    float a0 = b0[t], a1 = a0, a2 = a0, a3 = a0;
    for (int k = 0; k < 259; ++k) {
      float w = w0[k * 256 + t];
      a0 += in[0][k] * w; a1 += in[1][k] * w; a2 += in[2][k] * w; a3 += in[3][k] * w;
    }
    h1[0][t] = fmaxf(a0, 0.f); h1[1][t] = fmaxf(a1, 0.f);
    h1[2][t] = fmaxf(a2, 0.f); h1[3][t] = fmaxf(a3, 0.f);
  }
  __syncthreads();
  {  // L2: 256 -> 512
    float a0 = b1[t], a1 = a0, a2 = a0, a3 = a0;
    for (int k = 0; k < 256; ++k) {
      float w = w1[k * 512 + t];
      a0 += h1[0][k] * w; a1 += h1[1][k] * w; a2 += h1[2][k] * w; a3 += h1[3][k] * w;
    }
    h2[0][t] = fmaxf(a0, 0.f); h2[1][t] = fmaxf(a1, 0.f);
    h2[2][t] = fmaxf(a2, 0.f); h2[3][t] = fmaxf(a3, 0.f);
  }
  __syncthreads();
  {  // L3: 512 -> 1024, maxpool over 4 samples, global atomic max over groups
    float a[2][4];
#pragma unroll
    for (int p = 0; p < 2; ++p) {
      float bv = b2[t + p * 512];
      a[p][0] = bv; a[p][1] = bv; a[p][2] = bv; a[p][3] = bv;
    }
    for (int k = 0; k < 512; ++k) {
      float x0 = h2[0][k], x1 = h2[1][k], x2 = h2[2][k], x3 = h2[3][k];
      float wA = w2[k * 1024 + t];
      float wB = w2[k * 1024 + t + 512];
      a[0][0] += x0 * wA; a[0][1] += x1 * wA; a[0][2] += x2 * wA; a[0][3] += x3 * wA;
      a[1][0] += x0 * wB; a[1][1] += x1 * wB; a[1][2] += x2 * wB; a[1][3] += x3 * wB;
    }
#pragma unroll
    for (int p = 0; p < 2; ++p) {
      float vm = fmaxf(fmaxf(fmaxf(a[p][0], a[p][1]), fmaxf(a[p][2], a[p][3])), 0.f);
      atomicMax((unsigned*)l3f + (size_t)b * 1024 + t + p * 512, __float_as_uint(vm));
    }
  }
}

// ---------------------------------------------------------------- FC head
__global__ __launch_bounds__(256) void k_head(const float* __restrict__ l3f,
    const float* __restrict__ fc1w, const float* __restrict__ fc1b,
    const float* __restrict__ lg1, const float* __restrict__ lb1,
    const float* __restrict__ fc2w, const float* __restrict__ fc2b,
    const float* __restrict__ lg2, const float* __restrict__ lb2,
    const float* __restrict__ piw, const float* __restrict__ pib,
    const float* __restrict__ muw, const float* __restrict__ mub,
    const float* __restrict__ kw, const float* __restrict__ kb,
    float* __restrict__ out) {
  const int b = blockIdx.x, t = threadIdx.x;
  __shared__ float x[1024], x1[512], x2[256];
  __shared__ float red[8];
  __shared__ float hv[16];
  for (int i = t; i < 1024; i += 256) x[i] = l3f[(size_t)b * 1024 + i];
  __syncthreads();
  // fc1 (1024 -> 512), 2 outputs/thread
  float a0 = fc1b[t], a1 = fc1b[t + 256];
  for (int k = 0; k < 1024; ++k) {
    float xv = x[k];
    a0 += xv * fc1w[k * 512 + t];
    a1 += xv * fc1w[k * 512 + t + 256];
  }
  {  // LN1 (biased var) + relu
    float s = a0 + a1, ss = a0 * a0 + a1 * a1;
#pragma unroll
    for (int off = 32; off > 0; off >>= 1) { s += __shfl_down(s, off); ss += __shfl_down(ss, off); }
    if ((t & 63) == 0) { red[t >> 6] = s; red[4 + (t >> 6)] = ss; }
    __syncthreads();
    if (t == 0) {
      float S = red[0] + red[1] + red[2] + red[3];
      float SS = red[4] + red[5] + red[6] + red[7];
      float mean = S / 512.f;
      red[0] = mean; red[4] = SS / 512.f - mean * mean;
    }
    __syncthreads();
    float mean = red[0], var = red[4];
    float rs = rsqrtf(var + 1e-5f);
    x1[t]       = fmaxf((a0 - mean) * rs * lg1[t] + lb1[t], 0.f);
    x1[t + 256] = fmaxf((a1 - mean) * rs * lg1[t + 256] + lb1[t + 256], 0.f);
  }
  __syncthreads();
  // fc2 (512 -> 256)
  float a = fc2b[t];
  for (int k = 0; k < 512; ++k) a += x1[k] * fc2w[k * 256 + t];
  {  // LN2 + relu
    float s = a, ss = a * a;
#pragma unroll
    for (int off = 32; off > 0; off >>= 1) { s += __shfl_down(s, off); ss += __shfl_down(ss, off); }
    if ((t & 63) == 0) { red[t >> 6] = s; red[4 + (t >> 6)] = ss; }
    __syncthreads();
    if (t == 0) {
      float S = red[0] + red[1] + red[2] + red[3];
      float SS = red[4] + red[5] + red[6] + red[7];
      float mean = S / 256.f;
      red[0] = mean; red[4] = SS / 256.f - mean * mean;
    }
    __syncthreads();
    float mean = red[0], var = red[4];
    x2[t] = fmaxf((a - mean) * rsqrtf(var + 1e-5f) * lg2[t] + lb2[t], 0.f);
  }
  __syncthreads();
  // heads: 16 dot products over 256
  if (t < 16) {
    const float* W; const float* bb; int c; int C;
    if (t < 4)        { W = piw; bb = pib; c = t;      C = 4; }
    else if (t < 12)  { W = muw; bb = mub; c = t - 4;  C = 8; }
    else              { W = kw;  bb = kb;  c = t - 12; C = 4; }
    float acc = bb[c];
    for (int k = 0; k < 256; ++k) acc += x2[k] * W[k * C + c];
    hv[t] = acc;
  }
  __syncthreads();
  if (t == 0) {
    // softmax((pi)/0.7)
    float z[4], mx = -1e30f;
#pragma unroll
    for (int i = 0; i < 4; ++i) { z[i] = hv[i] / 0.7f; mx = fmaxf(mx, z[i]); }
    float e[4], sum = 0.f;
#pragma unroll
    for (int i = 0; i < 4; ++i) { e[i] = expf(z[i] - mx); sum += e[i]; }
#pragma unroll
    for (int k = 0; k < 4; ++k) {
      // mu
      float c0 = hv[4 + 2 * k], s0 = hv[4 + 2 * k + 1];
      float nr = sqrtf(c0 * c0 + s0 * s0);
      float den = fmaxf(nr, 1e-4f);
      float cu = c0 / den, su = s0 / den;
      float n2 = sqrtf(cu * cu + su * su);
      if (n2 < 1e-3f) { cu = 1.f; su = 0.f; }
      out[b * 4 + k] = atan2f(su, cu);
      // kappa
      float zk = hv[12 + k];
      float sp = fmaxf(zk, 0.f) + log1pf(expf(-fabsf(zk)));
      out[128 + b * 4 + k] = fminf(sp + 1e-6f, 80.f);
      // weight
      out[256 + b * 4 + k] = e[k] / sum;
    }
  }
}

// ---------------------------------------------------------------- launch
extern "C" void kernel_launch(void* const* d_in, const int* in_sizes, int n_in,
                              void* d_out, int out_size, void* d_ws, size_t ws_size,
                              hipStream_t stream) {
  const float* xyz  = (const float*)d_in[0];
  const float* s1w0 = (const float*)d_in[1];  const float* s1b0 = (const float*)d_in[2];
  const float* s1w1 = (const float*)d_in[3];  const float* s1b1 = (const float*)d_in[4];
  const float* s1w2 = (const float*)d_in[5];  const float* s1b2 = (const float*)d_in[6];
  const float* s2w0 = (const float*)d_in[7];  const float* s2b0 = (const float*)d_in[8];
  const float* s2w1 = (const float*)d_in[9];  const float* s2b1 = (const float*)d_in[10];
  const float* s2w2 = (const float*)d_in[11]; const float* s2b2 = (const float*)d_in[12];
  const float* s3w0 = (const float*)d_in[13]; const float* s3b0 = (const float*)d_in[14];
  const float* s3w1 = (const float*)d_in[15]; const float* s3b1 = (const float*)d_in[16];
  const float* s3w2 = (const float*)d_in[17]; const float* s3b2 = (const float*)d_in[18];
  const float* fc1w = (const float*)d_in[19]; const float* fc1b = (const float*)d_in[20];
  const float* lg1  = (const float*)d_in[21]; const float* lb1  = (const float*)d_in[22];
  const float* fc2w = (const float*)d_in[23]; const float* fc2b = (const float*)d_in[24];
  const float* lg2  = (const float*)d_in[25]; const float* lb2  = (const float*)d_in[26];
  const float* piw  = (const float*)d_in[27]; const float* pib  = (const float*)d_in[28];
  const float* muw  = (const float*)d_in[29]; const float* mub  = (const float*)d_in[30];
  const float* kw   = (const float*)d_in[31]; const float* kb   = (const float*)d_in[32];

  float* ws   = (float*)d_ws;
  float* l1x  = ws + OFF_L1X;
  float* g1   = ws + OFF_G1;
  float* l1f  = ws + OFF_L1F;
  float* l2x  = ws + OFF_L2X;
  int*   nid2 = (int*)(ws + OFF_NIDX2);
  float* l2f  = ws + OFF_L2F;
  float* l3f  = ws + OFF_L3F;
  float* out  = (float*)d_out;

  hipMemsetAsync(l3f, 0, (size_t)B * 1024 * sizeof(float), stream);
  k_fps1<<<B, 1024, 0, stream>>>(xyz, l1x);
  k_knn1<<<B * NP1, 256, 0, stream>>>(xyz, l1x, g1);
  k_mlp1<<<B * NP1, 256, 0, stream>>>(g1, s1w0, s1b0, s1w1, s1b1, s1w2, s1b2, l1f);
  k_fps2<<<B, 128, 0, stream>>>(l1x, l2x);
  k_knn2<<<B, 256, 0, stream>>>(l1x, l2x, nid2);
  k_mlp2<<<B * NP2, 256, 0, stream>>>(l1x, l2x, l1f, nid2,
                                      s2w0, s2b0, s2w1, s2b1, s2w2, s2b2, l2f);
  k_mlp3<<<B * 8, 512, 0, stream>>>(l2x, l2f, s3w0, s3b0, s3w1, s3b1, s3w2, s3b2, l3f);
  k_head<<<B, 256, 0, stream>>>(l3f, fc1w, fc1b, lg1, lb1, fc2w, fc2b, lg2, lb2,
                                piw, pib, muw, mub, kw, kb, out);
}